// Round 4
// baseline (246.737 us; speedup 1.0000x reference)
//
#include <hip/hip_runtime.h>

#define FEAT 64
#define CHUNK 1024   // counts per scan block

// ---- Pass 1: degree count (int atomics, 1 per edge) ----
__global__ void __launch_bounds__(256)
count_kernel(const int* __restrict__ dst, int* __restrict__ cnt, int E)
{
    int e = blockIdx.x * 256 + threadIdx.x;
    if (e < E) atomicAdd(&cnt[dst[e]], 1);
}

// ---- Pass 2a: per-chunk sums ----
__global__ void __launch_bounds__(256)
blocksum_kernel(const int* __restrict__ cnt, int* __restrict__ bsum, int N)
{
    __shared__ int red[256];
    int b = blockIdx.x, t = threadIdx.x;
    int base = b * CHUNK;
    int s = 0;
    for (int i = t; i < CHUNK; i += 256) {
        int idx = base + i;
        if (idx < N) s += cnt[idx];
    }
    red[t] = s; __syncthreads();
    for (int o = 128; o > 0; o >>= 1) {
        if (t < o) red[t] += red[t + o];
        __syncthreads();
    }
    if (t == 0) bsum[b] = red[0];
}

// ---- Pass 2b: exclusive scan of chunk sums (single block, B <= 256) ----
__global__ void __launch_bounds__(256)
scanbsum_kernel(int* __restrict__ bsum, int B)
{
    __shared__ int s[256];
    int t = threadIdx.x;
    int orig = (t < B) ? bsum[t] : 0;
    s[t] = orig; __syncthreads();
    for (int o = 1; o < 256; o <<= 1) {
        int v = (t >= o) ? s[t - o] : 0;
        __syncthreads();
        s[t] += v;
        __syncthreads();
    }
    if (t < B) bsum[t] = s[t] - orig;   // exclusive
}

// ---- Pass 2c: per-element exclusive offsets ----
__global__ void __launch_bounds__(256)
scatteroff_kernel(const int* __restrict__ cnt, const int* __restrict__ bsum,
                  int* __restrict__ off, int N, int E)
{
    __shared__ int s[256];
    int b = blockIdx.x, t = threadIdx.x;
    int base = b * CHUNK;
    int v0 = 0, v1 = 0, v2 = 0, v3 = 0;
    {
        int i = base + t * 4;
        if (i + 0 < N) v0 = cnt[i + 0];
        if (i + 1 < N) v1 = cnt[i + 1];
        if (i + 2 < N) v2 = cnt[i + 2];
        if (i + 3 < N) v3 = cnt[i + 3];
    }
    int loc = v0 + v1 + v2 + v3;
    int orig = loc;
    s[t] = loc; __syncthreads();
    for (int o = 1; o < 256; o <<= 1) {
        int u = (t >= o) ? s[t - o] : 0;
        __syncthreads();
        s[t] += u;
        __syncthreads();
    }
    int ex = s[t] - orig + bsum[b];
    int i = base + t * 4;
    if (i + 0 < N) off[i + 0] = ex; ex += v0;
    if (i + 1 < N) off[i + 1] = ex; ex += v1;
    if (i + 2 < N) off[i + 2] = ex; ex += v2;
    if (i + 3 < N) off[i + 3] = ex;
    if (b == 0 && t == 0) off[N] = E;
}

// ---- Pass 3: fill adjacency (src grouped by dst); consumes cnt to 0 ----
__global__ void __launch_bounds__(256)
fill_kernel(const int* __restrict__ src, const int* __restrict__ dst,
            const int* __restrict__ off, int* __restrict__ cnt,
            int* __restrict__ adj, int E)
{
    int e = blockIdx.x * 256 + threadIdx.x;
    if (e < E) {
        int d = dst[e];
        int p = atomicSub(&cnt[d], 1) - 1;
        adj[off[d] + p] = src[e];
    }
}

// ---- Pass 4: neighbor mean -> hn (stored in d_out). LDS-free for max
// occupancy. Wave = 8 nodes; lane = (nbr-slot 0..3, float4 0..15): one wave
// pulls 4 full 256B rows per dwordx4 issue, unroll x2 -> 8 rows in flight.
__global__ void __launch_bounds__(256)
gather_mean_kernel(const float* __restrict__ h, const int* __restrict__ adj,
                   const int* __restrict__ off, float* __restrict__ hn, int N)
{
    int t = threadIdx.x;
    int lane = t & 63, w = t >> 6;
    int sub = lane >> 4;     // neighbor slot 0..3
    int f4  = lane & 15;     // float4 index within 64-float row
    int nodeb = blockIdx.x * 32 + w * 8;
    for (int q = 0; q < 8; ++q) {
        int nd = nodeb + q;
        if (nd >= N) return;
        int o0 = off[nd], o1 = off[nd + 1];
        float s0 = 0.f, s1 = 0.f, s2 = 0.f, s3 = 0.f;
        for (int base = o0; base < o1; base += 8) {
            int e0 = base + sub, e1 = base + 4 + sub;
            if (e0 < o1) {
                float4 v = *(const float4*)&h[(size_t)adj[e0] * FEAT + f4 * 4];
                s0 += v.x; s1 += v.y; s2 += v.z; s3 += v.w;
            }
            if (e1 < o1) {
                float4 v = *(const float4*)&h[(size_t)adj[e1] * FEAT + f4 * 4];
                s0 += v.x; s1 += v.y; s2 += v.z; s3 += v.w;
            }
        }
        // reduce across the 4 neighbor slots (lane bits 4,5)
        s0 += __shfl_xor(s0, 16); s0 += __shfl_xor(s0, 32);
        s1 += __shfl_xor(s1, 16); s1 += __shfl_xor(s1, 32);
        s2 += __shfl_xor(s2, 16); s2 += __shfl_xor(s2, 32);
        s3 += __shfl_xor(s3, 16); s3 += __shfl_xor(s3, 32);
        float inv = 1.0f / fmaxf((float)(o1 - o0), 1.0f);
        if (sub == 0) {
            float4 m = make_float4(s0 * inv, s1 * inv, s2 * inv, s3 * inv);
            *(float4*)&hn[(size_t)nd * FEAT + f4 * 4] = m;
        }
    }
}

// ---- Pass 5: out[n] = relu(W1 @ h[n] + W2 @ hn[n] + b) ----
// hn lives in d_out; each wave reads only its own 8 nodes' hn rows then
// overwrites exactly those rows -> no cross-wave hazard (rows are 256B,
// line-aligned). x[node][k] is wave-uniform: pin node offsets to SGPR via
// readfirstlane so x loads become s_load (scalar cache), leaving only one
// LDS b128 (W) per 32 FMAs. W rows padded to 132: b128 bank-balanced.
__global__ void __launch_bounds__(256)
gemm_kernel(const float* __restrict__ h, float* hn_out,
            const float* __restrict__ W, const float* __restrict__ bias, int N)
{
    __shared__ float Wl[64][132];
    int t = threadIdx.x;
    {
        const float4* W4 = (const float4*)W;
        for (int i = t; i < 64 * 32; i += 256) {
            float4 v = W4[i];
            *(float4*)&Wl[i >> 5][(i & 31) * 4] = v;
        }
    }
    __syncthreads();

    int lane = t & 63, w = t >> 6;
    int nodeb = blockIdx.x * 32 + w * 8;
    float bj = bias[lane];

    float acc[8];
    const float* xh[8];
    const float* xn[8];
    #pragma unroll
    for (int q = 0; q < 8; ++q) {
        acc[q] = bj;
        int nd = nodeb + q;
        int ndc = (nd < N) ? nd : (N - 1);
        int xo = __builtin_amdgcn_readfirstlane(ndc << 6);   // nd*64, uniform
        xh[q] = h + xo;
        xn[q] = hn_out + xo;
    }

    #pragma unroll 4
    for (int k4 = 0; k4 < 16; ++k4) {            // self half: k = 0..63
        float4 wv = *(const float4*)&Wl[lane][k4 * 4];
        #pragma unroll
        for (int q = 0; q < 8; ++q) {
            float4 xv = *(const float4*)(xh[q] + k4 * 4);
            acc[q] += wv.x * xv.x;
            acc[q] += wv.y * xv.y;
            acc[q] += wv.z * xv.z;
            acc[q] += wv.w * xv.w;
        }
    }
    #pragma unroll 4
    for (int k4 = 0; k4 < 16; ++k4) {            // neighbor half: k = 64..127
        float4 wv = *(const float4*)&Wl[lane][64 + k4 * 4];
        #pragma unroll
        for (int q = 0; q < 8; ++q) {
            float4 xv = *(const float4*)(xn[q] + k4 * 4);
            acc[q] += wv.x * xv.x;
            acc[q] += wv.y * xv.y;
            acc[q] += wv.z * xv.z;
            acc[q] += wv.w * xv.w;
        }
    }

    #pragma unroll
    for (int q = 0; q < 8; ++q) {
        int nd = nodeb + q;
        if (nd < N)
            hn_out[(size_t)nd * FEAT + lane] = fmaxf(acc[q], 0.0f);
    }
}

extern "C" void kernel_launch(void* const* d_in, const int* in_sizes, int n_in,
                              void* d_out, int out_size, void* d_ws, size_t ws_size,
                              hipStream_t stream)
{
    const float* h   = (const float*)d_in[0];
    const int*   src = (const int*)d_in[1];
    const int*   dst = (const int*)d_in[2];
    const float* W   = (const float*)d_in[3];
    const float* b   = (const float*)d_in[4];
    float* out = (float*)d_out;

    int N = in_sizes[0] / FEAT;
    int E = in_sizes[1];

    // workspace (ints): cnt[N] | off[N+1] | adj[E] | bsum[256]  (~4.8 MB)
    int* cnt  = (int*)d_ws;
    int* off  = cnt + N;
    int* adj  = off + (N + 1);
    int* bsum = adj + E;

    hipMemsetAsync(cnt, 0, (size_t)N * sizeof(int), stream);

    int eblocks = (E + 255) / 256;
    count_kernel<<<eblocks, 256, 0, stream>>>(dst, cnt, E);

    int nchunks = (N + CHUNK - 1) / CHUNK;       // 98 for N=100K
    blocksum_kernel<<<nchunks, 256, 0, stream>>>(cnt, bsum, N);
    scanbsum_kernel<<<1, 256, 0, stream>>>(bsum, nchunks);
    scatteroff_kernel<<<nchunks, 256, 0, stream>>>(cnt, bsum, off, N, E);

    fill_kernel<<<eblocks, 256, 0, stream>>>(src, dst, off, cnt, adj, E);

    int gblocks = (N + 31) / 32;
    gather_mean_kernel<<<gblocks, 256, 0, stream>>>(h, adj, off, out, N);
    gemm_kernel<<<gblocks, 256, 0, stream>>>(h, out, W, b, N);
}

// Round 5
// 200.727 us; speedup vs baseline: 1.2292x; 1.2292x over previous
//
#include <hip/hip_runtime.h>

#define FEAT 64
#define CHUNK 1024   // counts per scan block
#define BN 64        // nodes per fused block
#define LDK 136      // padded bf16 row length: 272B rows -> 2-way banks (free)

typedef __attribute__((ext_vector_type(8))) __bf16 bf16x8;
typedef __attribute__((ext_vector_type(4))) float f32x4;

__device__ inline unsigned short f2bf(float f) {
    union { float f; unsigned u; } c; c.f = f;
    unsigned u = c.u;
    return (unsigned short)((u + 0x7fffu + ((u >> 16) & 1u)) >> 16);  // RNE
}

// ---- Pass 1: degree count (int atomics), 4 edges/thread ----
__global__ void __launch_bounds__(256)
count_kernel(const int* __restrict__ dst, int* __restrict__ cnt, int E)
{
    int i = (blockIdx.x * 256 + threadIdx.x) * 4;
    if (i + 3 < E) {
        int4 d = *(const int4*)&dst[i];
        atomicAdd(&cnt[d.x], 1); atomicAdd(&cnt[d.y], 1);
        atomicAdd(&cnt[d.z], 1); atomicAdd(&cnt[d.w], 1);
    } else {
        for (int e = i; e < E; ++e) atomicAdd(&cnt[dst[e]], 1);
    }
}

// ---- Pass 2a: per-chunk sums ----
__global__ void __launch_bounds__(256)
blocksum_kernel(const int* __restrict__ cnt, int* __restrict__ bsum, int N)
{
    __shared__ int red[256];
    int b = blockIdx.x, t = threadIdx.x;
    int base = b * CHUNK;
    int s = 0;
    for (int i = t; i < CHUNK; i += 256) {
        int idx = base + i;
        if (idx < N) s += cnt[idx];
    }
    red[t] = s; __syncthreads();
    for (int o = 128; o > 0; o >>= 1) {
        if (t < o) red[t] += red[t + o];
        __syncthreads();
    }
    if (t == 0) bsum[b] = red[0];
}

// ---- Pass 2b: exclusive scan of chunk sums (single block) ----
__global__ void __launch_bounds__(256)
scanbsum_kernel(int* __restrict__ bsum, int B)
{
    __shared__ int s[256];
    int t = threadIdx.x;
    int orig = (t < B) ? bsum[t] : 0;
    s[t] = orig; __syncthreads();
    for (int o = 1; o < 256; o <<= 1) {
        int v = (t >= o) ? s[t - o] : 0;
        __syncthreads();
        s[t] += v;
        __syncthreads();
    }
    if (t < B) bsum[t] = s[t] - orig;
}

// ---- Pass 2c: per-element exclusive offsets ----
__global__ void __launch_bounds__(256)
scatteroff_kernel(const int* __restrict__ cnt, const int* __restrict__ bsum,
                  int* __restrict__ off, int N, int E)
{
    __shared__ int s[256];
    int b = blockIdx.x, t = threadIdx.x;
    int base = b * CHUNK;
    int v0 = 0, v1 = 0, v2 = 0, v3 = 0;
    {
        int i = base + t * 4;
        if (i + 0 < N) v0 = cnt[i + 0];
        if (i + 1 < N) v1 = cnt[i + 1];
        if (i + 2 < N) v2 = cnt[i + 2];
        if (i + 3 < N) v3 = cnt[i + 3];
    }
    int loc = v0 + v1 + v2 + v3;
    int orig = loc;
    s[t] = loc; __syncthreads();
    for (int o = 1; o < 256; o <<= 1) {
        int u = (t >= o) ? s[t - o] : 0;
        __syncthreads();
        s[t] += u;
        __syncthreads();
    }
    int ex = s[t] - orig + bsum[b];
    int i = base + t * 4;
    if (i + 0 < N) off[i + 0] = ex; ex += v0;
    if (i + 1 < N) off[i + 1] = ex; ex += v1;
    if (i + 2 < N) off[i + 2] = ex; ex += v2;
    if (i + 3 < N) off[i + 3] = ex;
    if (b == 0 && t == 0) off[N] = E;
}

// ---- Pass 3: fill adjacency, 4 edges/thread; consumes cnt to 0 ----
__global__ void __launch_bounds__(256)
fill_kernel(const int* __restrict__ src, const int* __restrict__ dst,
            const int* __restrict__ off, int* __restrict__ cnt,
            int* __restrict__ adj, int E)
{
    int i = (blockIdx.x * 256 + threadIdx.x) * 4;
    if (i + 3 < E) {
        int4 sv = *(const int4*)&src[i];
        int4 dv = *(const int4*)&dst[i];
        int p;
        p = atomicSub(&cnt[dv.x], 1) - 1; adj[off[dv.x] + p] = sv.x;
        p = atomicSub(&cnt[dv.y], 1) - 1; adj[off[dv.y] + p] = sv.y;
        p = atomicSub(&cnt[dv.z], 1) - 1; adj[off[dv.z] + p] = sv.z;
        p = atomicSub(&cnt[dv.w], 1) - 1; adj[off[dv.w] + p] = sv.w;
    } else {
        for (int e = i; e < E; ++e) {
            int d = dst[e];
            int p = atomicSub(&cnt[d], 1) - 1;
            adj[off[d] + p] = src[e];
        }
    }
}

// ---- Pass 4: fused gather-mean (fp32) -> bf16 LDS tile -> MFMA GEMM ----
// 256 threads = 4 waves, 64 nodes/block. Gather: wave w owns 16 nodes;
// lane = (nbr-slot 0..3, float4 0..15): 4 rows per dwordx4 issue, x2 unroll.
// GEMM: x-tile [64][LDK] bf16 + W [64][LDK] bf16 in LDS; wave w computes
// M-tile w (16 nodes x 64 outputs) = 16 mfma_f32_16x16x32_bf16.
__global__ void __launch_bounds__(256)
sage_mfma_kernel(const float* __restrict__ h, const int* __restrict__ adj,
                 const int* __restrict__ off, const float* __restrict__ W,
                 const float* __restrict__ bias, float* __restrict__ out, int N)
{
    __shared__ unsigned short xl[BN * LDK];   // 17408 B
    __shared__ unsigned short Wl[64 * LDK];   // 17408 B

    int t = threadIdx.x;
    int lane = t & 63, w = t >> 6;
    int node0 = blockIdx.x * BN;

    // stage W (64x128 fp32) -> bf16 LDS, rows padded to LDK
    const float4* W4 = (const float4*)W;
    #pragma unroll
    for (int it = 0; it < 8; ++it) {
        int i = t + it * 256;               // 2048 float4 total
        float4 v = W4[i];
        int row = i >> 5, c4 = i & 31;
        *(ushort4*)&Wl[row * LDK + c4 * 4] =
            make_ushort4(f2bf(v.x), f2bf(v.y), f2bf(v.z), f2bf(v.w));
    }

    // stage self features -> xl[:, 0:64]
    #pragma unroll
    for (int it = 0; it < 4; ++it) {
        int i = t + it * 256;               // 1024 float4 total
        int n = i >> 4, c4 = i & 15;
        int node = node0 + n;
        float4 v = make_float4(0.f, 0.f, 0.f, 0.f);
        if (node < N) v = *(const float4*)&h[(size_t)node * FEAT + c4 * 4];
        *(ushort4*)&xl[n * LDK + c4 * 4] =
            make_ushort4(f2bf(v.x), f2bf(v.y), f2bf(v.z), f2bf(v.w));
    }

    // gather neighbor means (fp32 accumulate) -> xl[:, 64:128]
    int sub = lane >> 4, f4 = lane & 15;
    for (int q = 0; q < 16; ++q) {
        int nl = w * 16 + q;
        int node = node0 + nl;
        float s0 = 0.f, s1 = 0.f, s2 = 0.f, s3 = 0.f;
        int dg = 0;
        if (node < N) {
            int o0 = off[node], o1 = off[node + 1];
            dg = o1 - o0;
            for (int base = o0; base < o1; base += 8) {
                int e0 = base + sub, e1 = base + 4 + sub;
                if (e0 < o1) {
                    float4 v = *(const float4*)&h[(size_t)adj[e0] * FEAT + f4 * 4];
                    s0 += v.x; s1 += v.y; s2 += v.z; s3 += v.w;
                }
                if (e1 < o1) {
                    float4 v = *(const float4*)&h[(size_t)adj[e1] * FEAT + f4 * 4];
                    s0 += v.x; s1 += v.y; s2 += v.z; s3 += v.w;
                }
            }
        }
        s0 += __shfl_xor(s0, 16); s0 += __shfl_xor(s0, 32);
        s1 += __shfl_xor(s1, 16); s1 += __shfl_xor(s1, 32);
        s2 += __shfl_xor(s2, 16); s2 += __shfl_xor(s2, 32);
        s3 += __shfl_xor(s3, 16); s3 += __shfl_xor(s3, 32);
        if (sub == 0) {
            float inv = 1.0f / fmaxf((float)dg, 1.0f);
            *(ushort4*)&xl[nl * LDK + 64 + f4 * 4] =
                make_ushort4(f2bf(s0 * inv), f2bf(s1 * inv),
                             f2bf(s2 * inv), f2bf(s3 * inv));
        }
    }
    __syncthreads();

    // MFMA: wave w -> nodes [w*16, w*16+16). A-frag: 8 contig k of row
    // (lane&15); B-frag: 8 contig k of W row (ntile*16 + lane&15).
    f32x4 acc[4] = {};
    int arow = w * 16 + (lane & 15);
    int kg   = (lane >> 4) * 8;
    #pragma unroll
    for (int ks = 0; ks < 4; ++ks) {
        bf16x8 a = *(const bf16x8*)&xl[arow * LDK + ks * 32 + kg];
        #pragma unroll
        for (int nt = 0; nt < 4; ++nt) {
            bf16x8 b = *(const bf16x8*)&Wl[(nt * 16 + (lane & 15)) * LDK + ks * 32 + kg];
            acc[nt] = __builtin_amdgcn_mfma_f32_16x16x32_bf16(a, b, acc[nt], 0, 0, 0);
        }
    }

    // store: C/D layout col=lane&15, row=(lane>>4)*4+reg (m89-verified)
    int col   = lane & 15;
    int rbase = node0 + w * 16 + (lane >> 4) * 4;
    #pragma unroll
    for (int nt = 0; nt < 4; ++nt) {
        float bj = bias[nt * 16 + col];
        #pragma unroll
        for (int r = 0; r < 4; ++r) {
            int node = rbase + r;
            if (node < N) {
                float vv = acc[nt][r] + bj;
                out[(size_t)node * FEAT + nt * 16 + col] = fmaxf(vv, 0.f);
            }
        }
    }
}

extern "C" void kernel_launch(void* const* d_in, const int* in_sizes, int n_in,
                              void* d_out, int out_size, void* d_ws, size_t ws_size,
                              hipStream_t stream)
{
    const float* h   = (const float*)d_in[0];
    const int*   src = (const int*)d_in[1];
    const int*   dst = (const int*)d_in[2];
    const float* W   = (const float*)d_in[3];
    const float* b   = (const float*)d_in[4];
    float* out = (float*)d_out;

    int N = in_sizes[0] / FEAT;
    int E = in_sizes[1];

    // workspace (ints): cnt[N] | off[N+1] | adj[E] | bsum[256]  (~4.8 MB)
    int* cnt  = (int*)d_ws;
    int* off  = cnt + N;
    int* adj  = off + (N + 1);
    int* bsum = adj + E;

    hipMemsetAsync(cnt, 0, (size_t)N * sizeof(int), stream);

    int e4blocks = (E + 1023) / 1024;
    count_kernel<<<e4blocks, 256, 0, stream>>>(dst, cnt, E);

    int nchunks = (N + CHUNK - 1) / CHUNK;       // 98 for N=100K
    blocksum_kernel<<<nchunks, 256, 0, stream>>>(cnt, bsum, N);
    scanbsum_kernel<<<1, 256, 0, stream>>>(bsum, nchunks);
    scatteroff_kernel<<<nchunks, 256, 0, stream>>>(cnt, bsum, off, N, E);

    fill_kernel<<<e4blocks, 256, 0, stream>>>(src, dst, off, cnt, adj, E);

    int gblocks = (N + BN - 1) / BN;
    sage_mfma_kernel<<<gblocks, 256, 0, stream>>>(h, adj, off, W, b, out, N);
}

// Round 6
// 174.524 us; speedup vs baseline: 1.4138x; 1.1501x over previous
//
#include <hip/hip_runtime.h>

#define FEAT 64
#define CHUNK 1024   // counts per scan block
#define BN 64        // nodes per fused block
#define LDK 136      // padded bf16 row length: 272B rows -> 2-way banks (free)

typedef __attribute__((ext_vector_type(8))) __bf16 bf16x8;
typedef __attribute__((ext_vector_type(8))) unsigned short ushort8;
typedef __attribute__((ext_vector_type(4))) float f32x4;

__device__ inline unsigned short f2bf(float f) {
    union { float f; unsigned u; } c; c.f = f;
    unsigned u = c.u;
    return (unsigned short)((u + 0x7fffu + ((u >> 16) & 1u)) >> 16);  // RNE
}
__device__ inline float bf2f(unsigned short s) {
    union { unsigned u; float f; } c; c.u = ((unsigned)s) << 16; return c.f;
}

// ---- Pass 0: h fp32 -> bf16 (halves gather traffic) ----
__global__ void __launch_bounds__(256)
h2bf_kernel(const float* __restrict__ h, unsigned short* __restrict__ hbf, int total8)
{
    int i = blockIdx.x * 256 + threadIdx.x;     // one ushort8 per thread
    if (i < total8) {
        const float4* p = (const float4*)(h + (size_t)i * 8);
        float4 a = p[0], b = p[1];
        ushort8 v;
        v[0] = f2bf(a.x); v[1] = f2bf(a.y); v[2] = f2bf(a.z); v[3] = f2bf(a.w);
        v[4] = f2bf(b.x); v[5] = f2bf(b.y); v[6] = f2bf(b.z); v[7] = f2bf(b.w);
        *(ushort8*)(hbf + (size_t)i * 8) = v;
    }
}

// ---- Pass 1: degree count (int atomics), 4 edges/thread ----
__global__ void __launch_bounds__(256)
count_kernel(const int* __restrict__ dst, int* __restrict__ cnt, int E)
{
    int i = (blockIdx.x * 256 + threadIdx.x) * 4;
    if (i + 3 < E) {
        int4 d = *(const int4*)&dst[i];
        atomicAdd(&cnt[d.x], 1); atomicAdd(&cnt[d.y], 1);
        atomicAdd(&cnt[d.z], 1); atomicAdd(&cnt[d.w], 1);
    } else {
        for (int e = i; e < E; ++e) atomicAdd(&cnt[dst[e]], 1);
    }
}

// ---- Pass 2a: per-chunk sums ----
__global__ void __launch_bounds__(256)
blocksum_kernel(const int* __restrict__ cnt, int* __restrict__ bsum, int N)
{
    __shared__ int red[256];
    int b = blockIdx.x, t = threadIdx.x;
    int base = b * CHUNK;
    int s = 0;
    for (int i = t; i < CHUNK; i += 256) {
        int idx = base + i;
        if (idx < N) s += cnt[idx];
    }
    red[t] = s; __syncthreads();
    for (int o = 128; o > 0; o >>= 1) {
        if (t < o) red[t] += red[t + o];
        __syncthreads();
    }
    if (t == 0) bsum[b] = red[0];
}

// ---- Pass 2b: exclusive scan of chunk sums (single block) ----
__global__ void __launch_bounds__(256)
scanbsum_kernel(int* __restrict__ bsum, int B)
{
    __shared__ int s[256];
    int t = threadIdx.x;
    int orig = (t < B) ? bsum[t] : 0;
    s[t] = orig; __syncthreads();
    for (int o = 1; o < 256; o <<= 1) {
        int v = (t >= o) ? s[t - o] : 0;
        __syncthreads();
        s[t] += v;
        __syncthreads();
    }
    if (t < B) bsum[t] = s[t] - orig;
}

// ---- Pass 2c: per-element exclusive offsets ----
__global__ void __launch_bounds__(256)
scatteroff_kernel(const int* __restrict__ cnt, const int* __restrict__ bsum,
                  int* __restrict__ off, int N, int E)
{
    __shared__ int s[256];
    int b = blockIdx.x, t = threadIdx.x;
    int base = b * CHUNK;
    int v0 = 0, v1 = 0, v2 = 0, v3 = 0;
    {
        int i = base + t * 4;
        if (i + 0 < N) v0 = cnt[i + 0];
        if (i + 1 < N) v1 = cnt[i + 1];
        if (i + 2 < N) v2 = cnt[i + 2];
        if (i + 3 < N) v3 = cnt[i + 3];
    }
    int loc = v0 + v1 + v2 + v3;
    int orig = loc;
    s[t] = loc; __syncthreads();
    for (int o = 1; o < 256; o <<= 1) {
        int u = (t >= o) ? s[t - o] : 0;
        __syncthreads();
        s[t] += u;
        __syncthreads();
    }
    int ex = s[t] - orig + bsum[b];
    int i = base + t * 4;
    if (i + 0 < N) off[i + 0] = ex; ex += v0;
    if (i + 1 < N) off[i + 1] = ex; ex += v1;
    if (i + 2 < N) off[i + 2] = ex; ex += v2;
    if (i + 3 < N) off[i + 3] = ex;
    if (b == 0 && t == 0) off[N] = E;
}

// ---- Pass 3: fill adjacency, 4 edges/thread; consumes cnt to 0 ----
__global__ void __launch_bounds__(256)
fill_kernel(const int* __restrict__ src, const int* __restrict__ dst,
            const int* __restrict__ off, int* __restrict__ cnt,
            int* __restrict__ adj, int E)
{
    int i = (blockIdx.x * 256 + threadIdx.x) * 4;
    if (i + 3 < E) {
        int4 sv = *(const int4*)&src[i];
        int4 dv = *(const int4*)&dst[i];
        int p;
        p = atomicSub(&cnt[dv.x], 1) - 1; adj[off[dv.x] + p] = sv.x;
        p = atomicSub(&cnt[dv.y], 1) - 1; adj[off[dv.y] + p] = sv.y;
        p = atomicSub(&cnt[dv.z], 1) - 1; adj[off[dv.z] + p] = sv.z;
        p = atomicSub(&cnt[dv.w], 1) - 1; adj[off[dv.w] + p] = sv.w;
    } else {
        for (int e = i; e < E; ++e) {
            int d = dst[e];
            int p = atomicSub(&cnt[d], 1) - 1;
            adj[off[d] + p] = src[e];
        }
    }
}

// ---- Pass 4: fused gather-mean (bf16 in, fp32 acc) -> bf16 LDS -> MFMA ----
// 256 threads = 4 waves, 64 nodes/block; wave owns a 16-node strip.
// Gather: lane = (slot 0..7, ushort8 0..7): 8 bf16 rows (128B each) per
// issue; slots A+B issued together -> 16 rows in flight; next node's off/adj
// prefetched during current node's row latency. Tail loop for deg > 16.
__global__ void __launch_bounds__(256)
sage_mfma_kernel(const unsigned short* __restrict__ hbf, const int* __restrict__ adj,
                 const int* __restrict__ off, const float* __restrict__ W,
                 const float* __restrict__ bias, float* __restrict__ out, int N)
{
    __shared__ unsigned short xl[BN * LDK];   // 17408 B
    __shared__ unsigned short Wl[64 * LDK];   // 17408 B

    int t = threadIdx.x;
    int lane = t & 63, w = t >> 6;
    int node0 = blockIdx.x * BN;

    // stage W (64x128 fp32) -> bf16 LDS
    const float4* W4 = (const float4*)W;
    #pragma unroll
    for (int it = 0; it < 8; ++it) {
        int i = t + it * 256;               // 2048 float4 total
        float4 v = W4[i];
        int row = i >> 5, c4 = i & 31;
        *(ushort4*)&Wl[row * LDK + c4 * 4] =
            make_ushort4(f2bf(v.x), f2bf(v.y), f2bf(v.z), f2bf(v.w));
    }

    // stage self features -> xl[:, 0:64] (straight bf16 copy)
    #pragma unroll
    for (int it = 0; it < 2; ++it) {
        int i = t + it * 256;               // 512 ushort8 total
        int n = i >> 3, c8 = i & 7;
        int node = node0 + n;
        ushort8 v = {};
        if (node < N) v = *(const ushort8*)&hbf[(size_t)node * FEAT + c8 * 8];
        *(ushort8*)&xl[n * LDK + c8 * 8] = v;
    }

    // gather neighbor means -> xl[:, 64:128]
    {
        int sub = lane >> 3;    // edge slot 0..7
        int f8  = lane & 7;     // ushort8 index within row
        int wnode0 = node0 + w * 16;

        int o0 = 0, o1 = 0;
        if (wnode0 < N) { o0 = off[wnode0]; o1 = off[wnode0 + 1]; }
        int idxA = (o0 + sub     < o1) ? adj[o0 + sub]     : -1;
        int idxB = (o0 + 8 + sub < o1) ? adj[o0 + 8 + sub] : -1;

        for (int q = 0; q < 16; ++q) {
            int node = wnode0 + q;
            int o2 = o1;
            if (q < 15 && node + 1 < N) o2 = off[node + 2];

            // issue this node's first-16-edge row loads
            ushort8 rA, rB;
            bool vA = (idxA >= 0), vB = (idxB >= 0);
            if (vA) rA = *(const ushort8*)&hbf[(size_t)idxA * FEAT + f8 * 8];
            if (vB) rB = *(const ushort8*)&hbf[(size_t)idxB * FEAT + f8 * 8];

            // prefetch next node's first-16 adj (overlaps row latency)
            int nA = -1, nB = -1;
            if (q < 15) {
                nA = (o1 + sub     < o2) ? adj[o1 + sub]     : -1;
                nB = (o1 + 8 + sub < o2) ? adj[o1 + 8 + sub] : -1;
            }

            float acc[8] = {0.f, 0.f, 0.f, 0.f, 0.f, 0.f, 0.f, 0.f};
            if (vA) {
                #pragma unroll
                for (int j = 0; j < 8; ++j) acc[j] += bf2f(rA[j]);
            }
            if (vB) {
                #pragma unroll
                for (int j = 0; j < 8; ++j) acc[j] += bf2f(rB[j]);
            }
            // rare tail: deg > 16
            for (int base = o0 + 16; base < o1; base += 8) {
                int e = base + sub;
                if (e < o1) {
                    ushort8 r = *(const ushort8*)&hbf[(size_t)adj[e] * FEAT + f8 * 8];
                    #pragma unroll
                    for (int j = 0; j < 8; ++j) acc[j] += bf2f(r[j]);
                }
            }

            // butterfly reduce across 8 slots (lane bits 3,4,5)
            #pragma unroll
            for (int j = 0; j < 8; ++j) {
                float v = acc[j];
                v += __shfl_xor(v, 8);
                v += __shfl_xor(v, 16);
                v += __shfl_xor(v, 32);
                acc[j] = v;
            }
            if (sub == 0) {
                float inv = 1.0f / fmaxf((float)(o1 - o0), 1.0f);
                ushort8 m;
                #pragma unroll
                for (int j = 0; j < 8; ++j) m[j] = f2bf(acc[j] * inv);
                *(ushort8*)&xl[(w * 16 + q) * LDK + 64 + f8 * 8] = m;
            }
            o0 = o1; o1 = o2; idxA = nA; idxB = nB;
        }
    }
    __syncthreads();

    // MFMA: wave w -> nodes [w*16, w*16+16). 16 x mfma_f32_16x16x32_bf16.
    f32x4 acc[4] = {};
    int arow = w * 16 + (lane & 15);
    int kg   = (lane >> 4) * 8;
    #pragma unroll
    for (int ks = 0; ks < 4; ++ks) {
        bf16x8 a = *(const bf16x8*)&xl[arow * LDK + ks * 32 + kg];
        #pragma unroll
        for (int nt = 0; nt < 4; ++nt) {
            bf16x8 b = *(const bf16x8*)&Wl[(nt * 16 + (lane & 15)) * LDK + ks * 32 + kg];
            acc[nt] = __builtin_amdgcn_mfma_f32_16x16x32_bf16(a, b, acc[nt], 0, 0, 0);
        }
    }

    // store: C/D layout col=lane&15, row=(lane>>4)*4+reg (m89-verified)
    int col   = lane & 15;
    int rbase = node0 + w * 16 + (lane >> 4) * 4;
    #pragma unroll
    for (int nt = 0; nt < 4; ++nt) {
        float bj = bias[nt * 16 + col];
        #pragma unroll
        for (int r = 0; r < 4; ++r) {
            int node = rbase + r;
            if (node < N) {
                float vv = acc[nt][r] + bj;
                out[(size_t)node * FEAT + nt * 16 + col] = fmaxf(vv, 0.f);
            }
        }
    }
}

extern "C" void kernel_launch(void* const* d_in, const int* in_sizes, int n_in,
                              void* d_out, int out_size, void* d_ws, size_t ws_size,
                              hipStream_t stream)
{
    const float* h   = (const float*)d_in[0];
    const int*   src = (const int*)d_in[1];
    const int*   dst = (const int*)d_in[2];
    const float* W   = (const float*)d_in[3];
    const float* b   = (const float*)d_in[4];
    float* out = (float*)d_out;

    int N = in_sizes[0] / FEAT;
    int E = in_sizes[1];

    // ws: hbf[N*64 ushort] | cnt[N] | off[N+1] | adj[E] | bsum[256]  (~17.6 MB)
    unsigned short* hbf = (unsigned short*)d_ws;
    int* cnt  = (int*)(hbf + (size_t)N * FEAT);
    int* off  = cnt + N;
    int* adj  = off + (N + 1);
    int* bsum = adj + E;

    hipMemsetAsync(cnt, 0, (size_t)N * sizeof(int), stream);

    int total8 = N * (FEAT / 8);
    h2bf_kernel<<<(total8 + 255) / 256, 256, 0, stream>>>(h, hbf, total8);

    int e4blocks = (E + 1023) / 1024;
    count_kernel<<<e4blocks, 256, 0, stream>>>(dst, cnt, E);

    int nchunks = (N + CHUNK - 1) / CHUNK;       // 98 for N=100K
    blocksum_kernel<<<nchunks, 256, 0, stream>>>(cnt, bsum, N);
    scanbsum_kernel<<<1, 256, 0, stream>>>(bsum, nchunks);
    scatteroff_kernel<<<nchunks, 256, 0, stream>>>(cnt, bsum, off, N, E);

    fill_kernel<<<e4blocks, 256, 0, stream>>>(src, dst, off, cnt, adj, E);

    int gblocks = (N + BN - 1) / BN;
    sage_mfma_kernel<<<gblocks, 256, 0, stream>>>(hbf, adj, off, W, b, out, N);
}

// Round 7
// 134.107 us; speedup vs baseline: 1.8399x; 1.3014x over previous
//
#include <hip/hip_runtime.h>

#define FEAT 64
#define BN 64        // nodes per fused block
#define LDK 136      // padded bf16 row length: 272B rows -> 2-way banks (free)

typedef __attribute__((ext_vector_type(8))) __bf16 bf16x8;
typedef __attribute__((ext_vector_type(8))) unsigned short ushort8;
typedef __attribute__((ext_vector_type(4))) float f32x4;

__device__ inline unsigned short f2bf(float f) {
    union { float f; unsigned u; } c; c.f = f;
    unsigned u = c.u;
    return (unsigned short)((u + 0x7fffu + ((u >> 16) & 1u)) >> 16);  // RNE
}
__device__ inline float bf2f(unsigned short s) {
    union { unsigned u; float f; } c; c.u = ((unsigned)s) << 16; return c.f;
}

// ---- Pass 0: h fp32 -> bf16 (halves gather traffic) ----
__global__ void __launch_bounds__(256)
h2bf_kernel(const float* __restrict__ h, unsigned short* __restrict__ hbf, int total8)
{
    int i = blockIdx.x * 256 + threadIdx.x;     // one ushort8 per thread
    if (i < total8) {
        const float4* p = (const float4*)(h + (size_t)i * 8);
        float4 a = p[0], b = p[1];
        ushort8 v;
        v[0] = f2bf(a.x); v[1] = f2bf(a.y); v[2] = f2bf(a.z); v[3] = f2bf(a.w);
        v[4] = f2bf(b.x); v[5] = f2bf(b.y); v[6] = f2bf(b.z); v[7] = f2bf(b.w);
        *(ushort8*)(hbf + (size_t)i * 8) = v;
    }
}

// ---- A1: bucket histogram (bucket = dst >> shift, <= 256 buckets) ----
__global__ void __launch_bounds__(256)
hist_kernel(const int* __restrict__ dst, int* __restrict__ bsize, int E, int shift)
{
    __shared__ int hist[256];
    int t = threadIdx.x;
    hist[t] = 0; __syncthreads();
    int i = (blockIdx.x * 256 + t) * 4;
    if (i + 3 < E) {
        int4 d = *(const int4*)&dst[i];
        atomicAdd(&hist[d.x >> shift], 1);
        atomicAdd(&hist[d.y >> shift], 1);
        atomicAdd(&hist[d.z >> shift], 1);
        atomicAdd(&hist[d.w >> shift], 1);
    } else {
        for (int e = i; e < E; ++e) atomicAdd(&hist[dst[e] >> shift], 1);
    }
    __syncthreads();
    if (hist[t]) atomicAdd(&bsize[t], hist[t]);
}

// ---- A2: exclusive scan of bucket sizes (single block) ----
__global__ void __launch_bounds__(256)
bscan_kernel(const int* __restrict__ bsize, int* __restrict__ bases,
             int* __restrict__ cursors, int NB, int E)
{
    __shared__ int s[256];
    int t = threadIdx.x;
    int v = (t < NB) ? bsize[t] : 0;
    s[t] = v; __syncthreads();
    for (int o = 1; o < 256; o <<= 1) {
        int u = (t >= o) ? s[t - o] : 0;
        __syncthreads();
        s[t] += u; __syncthreads();
    }
    int ex = s[t] - v;
    if (t < NB) { bases[t] = ex; cursors[t] = ex; }
    if (t == 0) bases[NB] = E;
}

// ---- A3: scatter (src,dst) pairs into bucket regions. Per-block LDS
// histogram -> one global atomicAdd per bucket reserves a chunk -> pairs
// written grouped by bucket (~21-edge ~168B runs: minimal write amp). ----
__global__ void __launch_bounds__(256)
scatter_pairs_kernel(const int* __restrict__ src, const int* __restrict__ dst,
                     int* __restrict__ cursors, int2* __restrict__ pairs,
                     int E, int shift)
{
    __shared__ int hist[256];
    __shared__ int chunk[256];
    int t = threadIdx.x;
    hist[t] = 0;
    __syncthreads();
    int base = blockIdx.x * 4096;
    int s_[16], d_[16];
    #pragma unroll
    for (int r = 0; r < 4; ++r) {
        int e = base + r * 1024 + t * 4;
        if (e + 3 < E) {
            *(int4*)&s_[r * 4] = *(const int4*)&src[e];
            *(int4*)&d_[r * 4] = *(const int4*)&dst[e];
        } else {
            #pragma unroll
            for (int j = 0; j < 4; ++j) {
                int ee = e + j;
                s_[r * 4 + j] = (ee < E) ? src[ee] : -1;
                d_[r * 4 + j] = (ee < E) ? dst[ee] : -1;
            }
        }
    }
    #pragma unroll
    for (int i = 0; i < 16; ++i)
        if (d_[i] >= 0) atomicAdd(&hist[d_[i] >> shift], 1);
    __syncthreads();
    chunk[t] = hist[t] ? atomicAdd(&cursors[t], hist[t]) : 0;
    hist[t] = 0;
    __syncthreads();
    #pragma unroll
    for (int i = 0; i < 16; ++i) {
        if (d_[i] >= 0) {
            int bk = d_[i] >> shift;
            int pos = atomicAdd(&hist[bk], 1);
            pairs[chunk[bk] + pos] = make_int2(s_[i], d_[i]);
        }
    }
}

// ---- B: per-bucket counting sort -> off + adj. One block per bucket;
// bucket's adj region is contiguous (~20KB, L2-resident): write amp ~1. ----
__global__ void __launch_bounds__(256)
bucket_csr_kernel(const int2* __restrict__ pairs, const int* __restrict__ bases,
                  int* __restrict__ off, int* __restrict__ adj,
                  int N, int E, int shift)
{
    __shared__ int cnt[512];
    __shared__ int sums[256];
    int b = blockIdx.x, t = threadIdx.x;
    int nb0 = b << shift;
    int nn = min(1 << shift, N - nb0);
    cnt[t] = 0; cnt[t + 256] = 0;
    __syncthreads();
    int e0 = bases[b], e1 = bases[b + 1];
    for (int e = e0 + t; e < e1; e += 256) {
        int2 p = pairs[e];
        atomicAdd(&cnt[p.y - nb0], 1);
    }
    __syncthreads();
    int a = cnt[2 * t], c = cnt[2 * t + 1];
    int s = a + c;
    sums[t] = s; __syncthreads();
    for (int o = 1; o < 256; o <<= 1) {
        int u = (t >= o) ? sums[t - o] : 0;
        __syncthreads();
        sums[t] += u; __syncthreads();
    }
    int ex = sums[t] - s;
    if (2 * t     < nn) off[nb0 + 2 * t]     = e0 + ex;
    if (2 * t + 1 < nn) off[nb0 + 2 * t + 1] = e0 + ex + a;
    cnt[2 * t] = ex; cnt[2 * t + 1] = ex + a;
    __syncthreads();
    for (int e = e0 + t; e < e1; e += 256) {
        int2 p = pairs[e];
        int pos = atomicAdd(&cnt[p.y - nb0], 1);
        adj[e0 + pos] = p.x;
    }
    if (b == 0 && t == 0) off[N] = E;
}

// ---- Pass 4: fused gather-mean (bf16 in, fp32 acc) -> bf16 LDS -> MFMA ----
__global__ void __launch_bounds__(256)
sage_mfma_kernel(const unsigned short* __restrict__ hbf, const int* __restrict__ adj,
                 const int* __restrict__ off, const float* __restrict__ W,
                 const float* __restrict__ bias, float* __restrict__ out, int N)
{
    __shared__ unsigned short xl[BN * LDK];   // 17408 B
    __shared__ unsigned short Wl[64 * LDK];   // 17408 B

    int t = threadIdx.x;
    int lane = t & 63, w = t >> 6;
    int node0 = blockIdx.x * BN;

    // stage W (64x128 fp32) -> bf16 LDS
    const float4* W4 = (const float4*)W;
    #pragma unroll
    for (int it = 0; it < 8; ++it) {
        int i = t + it * 256;               // 2048 float4 total
        float4 v = W4[i];
        int row = i >> 5, c4 = i & 31;
        *(ushort4*)&Wl[row * LDK + c4 * 4] =
            make_ushort4(f2bf(v.x), f2bf(v.y), f2bf(v.z), f2bf(v.w));
    }

    // stage self features -> xl[:, 0:64] (straight bf16 copy)
    #pragma unroll
    for (int it = 0; it < 2; ++it) {
        int i = t + it * 256;               // 512 ushort8 total
        int n = i >> 3, c8 = i & 7;
        int node = node0 + n;
        ushort8 v = {};
        if (node < N) v = *(const ushort8*)&hbf[(size_t)node * FEAT + c8 * 8];
        *(ushort8*)&xl[n * LDK + c8 * 8] = v;
    }

    // gather neighbor means -> xl[:, 64:128]
    {
        int sub = lane >> 3;    // edge slot 0..7
        int f8  = lane & 7;     // ushort8 index within row
        int wnode0 = node0 + w * 16;

        int o0 = 0, o1 = 0;
        if (wnode0 < N) { o0 = off[wnode0]; o1 = off[wnode0 + 1]; }
        int idxA = (o0 + sub     < o1) ? adj[o0 + sub]     : -1;
        int idxB = (o0 + 8 + sub < o1) ? adj[o0 + 8 + sub] : -1;

        for (int q = 0; q < 16; ++q) {
            int node = wnode0 + q;
            int o2 = o1;
            if (q < 15 && node + 1 < N) o2 = off[node + 2];

            // issue this node's first-16-edge row loads
            ushort8 rA, rB;
            bool vA = (idxA >= 0), vB = (idxB >= 0);
            if (vA) rA = *(const ushort8*)&hbf[(size_t)idxA * FEAT + f8 * 8];
            if (vB) rB = *(const ushort8*)&hbf[(size_t)idxB * FEAT + f8 * 8];

            // prefetch next node's first-16 adj (overlaps row latency)
            int nA = -1, nB = -1;
            if (q < 15) {
                nA = (o1 + sub     < o2) ? adj[o1 + sub]     : -1;
                nB = (o1 + 8 + sub < o2) ? adj[o1 + 8 + sub] : -1;
            }

            float acc[8] = {0.f, 0.f, 0.f, 0.f, 0.f, 0.f, 0.f, 0.f};
            if (vA) {
                #pragma unroll
                for (int j = 0; j < 8; ++j) acc[j] += bf2f(rA[j]);
            }
            if (vB) {
                #pragma unroll
                for (int j = 0; j < 8; ++j) acc[j] += bf2f(rB[j]);
            }
            // rare tail: deg > 16
            for (int base = o0 + 16; base < o1; base += 8) {
                int e = base + sub;
                if (e < o1) {
                    ushort8 r = *(const ushort8*)&hbf[(size_t)adj[e] * FEAT + f8 * 8];
                    #pragma unroll
                    for (int j = 0; j < 8; ++j) acc[j] += bf2f(r[j]);
                }
            }

            // butterfly reduce across 8 slots (lane bits 3,4,5)
            #pragma unroll
            for (int j = 0; j < 8; ++j) {
                float v = acc[j];
                v += __shfl_xor(v, 8);
                v += __shfl_xor(v, 16);
                v += __shfl_xor(v, 32);
                acc[j] = v;
            }
            if (sub == 0) {
                float inv = 1.0f / fmaxf((float)(o1 - o0), 1.0f);
                ushort8 m;
                #pragma unroll
                for (int j = 0; j < 8; ++j) m[j] = f2bf(acc[j] * inv);
                *(ushort8*)&xl[(w * 16 + q) * LDK + 64 + f8 * 8] = m;
            }
            o0 = o1; o1 = o2; idxA = nA; idxB = nB;
        }
    }
    __syncthreads();

    // MFMA: wave w -> nodes [w*16, w*16+16). 16 x mfma_f32_16x16x32_bf16.
    f32x4 acc[4] = {};
    int arow = w * 16 + (lane & 15);
    int kg   = (lane >> 4) * 8;
    #pragma unroll
    for (int ks = 0; ks < 4; ++ks) {
        bf16x8 a = *(const bf16x8*)&xl[arow * LDK + ks * 32 + kg];
        #pragma unroll
        for (int nt = 0; nt < 4; ++nt) {
            bf16x8 b = *(const bf16x8*)&Wl[(nt * 16 + (lane & 15)) * LDK + ks * 32 + kg];
            acc[nt] = __builtin_amdgcn_mfma_f32_16x16x32_bf16(a, b, acc[nt], 0, 0, 0);
        }
    }

    // store: C/D layout col=lane&15, row=(lane>>4)*4+reg (m89-verified)
    int col   = lane & 15;
    int rbase = node0 + w * 16 + (lane >> 4) * 4;
    #pragma unroll
    for (int nt = 0; nt < 4; ++nt) {
        float bj = bias[nt * 16 + col];
        #pragma unroll
        for (int r = 0; r < 4; ++r) {
            int node = rbase + r;
            if (node < N) {
                float vv = acc[nt][r] + bj;
                out[(size_t)node * FEAT + nt * 16 + col] = fmaxf(vv, 0.f);
            }
        }
    }
}

extern "C" void kernel_launch(void* const* d_in, const int* in_sizes, int n_in,
                              void* d_out, int out_size, void* d_ws, size_t ws_size,
                              hipStream_t stream)
{
    const float* h   = (const float*)d_in[0];
    const int*   src = (const int*)d_in[1];
    const int*   dst = (const int*)d_in[2];
    const float* W   = (const float*)d_in[3];
    const float* b   = (const float*)d_in[4];
    float* out = (float*)d_out;

    int N = in_sizes[0] / FEAT;
    int E = in_sizes[1];

    // bucket shift: buckets = dst>>shift, at most 256 buckets
    int shift = 0;
    while (((N - 1) >> shift) >= 256) ++shift;     // N=100K -> shift=9, NB=196
    int NB = ((N - 1) >> shift) + 1;

    // ws: hbf[N*64 ush] | pairs[E int2] | adj[E] | off[N+1] | bsize/bases/cursors
    // = 12.8 + 8 + 4 + 0.4 + ~0.01 MB  (~25.2 MB, <= proven round-1 usage)
    unsigned short* hbf = (unsigned short*)d_ws;
    int2* pairs   = (int2*)(hbf + (size_t)N * FEAT);
    int*  adj     = (int*)(pairs + E);
    int*  off     = adj + E;
    int*  bsize   = off + (N + 1);
    int*  bases   = bsize + 256;
    int*  cursors = bases + 257;

    hipMemsetAsync(bsize, 0, 256 * sizeof(int), stream);

    int total8 = N * (FEAT / 8);
    h2bf_kernel<<<(total8 + 255) / 256, 256, 0, stream>>>(h, hbf, total8);

    int e4blocks = (E + 1023) / 1024;
    hist_kernel<<<e4blocks, 256, 0, stream>>>(dst, bsize, E, shift);

    bscan_kernel<<<1, 256, 0, stream>>>(bsize, bases, cursors, NB, E);

    int spblocks = (E + 4095) / 4096;
    scatter_pairs_kernel<<<spblocks, 256, 0, stream>>>(src, dst, cursors, pairs, E, shift);

    bucket_csr_kernel<<<NB, 256, 0, stream>>>(pairs, bases, off, adj, N, E, shift);

    int gblocks = (N + BN - 1) / BN;
    sage_mfma_kernel<<<gblocks, 256, 0, stream>>>(hbf, adj, off, W, b, out, N);
}

// Round 8
// 131.395 us; speedup vs baseline: 1.8778x; 1.0206x over previous
//
#include <hip/hip_runtime.h>

#define FEAT 64
#define BN 128       // nodes per fused block (8 waves x 16 nodes)

typedef __attribute__((ext_vector_type(8))) __bf16 bf16x8;
typedef __attribute__((ext_vector_type(8))) unsigned short ushort8;
typedef __attribute__((ext_vector_type(4))) float f32x4;

__device__ inline unsigned short f2bf(float f) {
    union { float f; unsigned u; } c; c.f = f;
    unsigned u = c.u;
    return (unsigned short)((u + 0x7fffu + ((u >> 16) & 1u)) >> 16);  // RNE
}
__device__ inline float bf2f(unsigned short s) {
    union { unsigned u; float f; } c; c.u = ((unsigned)s) << 16; return c.f;
}

// ---- Prep (fused): [0,h2bfB) h fp32->bf16 | [h2bfB,+4) W->Wfrag bf16 |
// rest: bucket histogram of dst>>shift ----
__global__ void __launch_bounds__(256)
prep_kernel(const float* __restrict__ h, unsigned short* __restrict__ hbf,
            int total8, const float* __restrict__ W, unsigned short* __restrict__ wfg,
            const int* __restrict__ dst, int* __restrict__ bsize, int E,
            int shift, int h2bfB)
{
    __shared__ int hist[256];
    int bid = blockIdx.x, t = threadIdx.x;

    if (bid < h2bfB) {                       // h fp32 -> bf16
        int i = bid * 256 + t;
        if (i < total8) {
            const float4* p = (const float4*)(h + (size_t)i * 8);
            float4 a = p[0], b = p[1];
            ushort8 v;
            v[0] = f2bf(a.x); v[1] = f2bf(a.y); v[2] = f2bf(a.z); v[3] = f2bf(a.w);
            v[4] = f2bf(b.x); v[5] = f2bf(b.y); v[6] = f2bf(b.z); v[7] = f2bf(b.w);
            *(ushort8*)(hbf + (size_t)i * 8) = v;
        }
        return;
    }
    if (bid < h2bfB + 4) {                   // W (64x128 f32) -> frag-order bf16
        int i = (bid - h2bfB) * 256 + t;     // 0..1023 = (ks*4+nt)*64 + lane
        int ksnt = i >> 6, lane = i & 63;
        int row = (ksnt & 3) * 16 + (lane & 15);
        int kb  = (ksnt >> 2) * 32 + (lane >> 4) * 8;
        const float4* p = (const float4*)(W + row * 128 + kb);
        float4 a = p[0], b = p[1];
        ushort8 v;
        v[0] = f2bf(a.x); v[1] = f2bf(a.y); v[2] = f2bf(a.z); v[3] = f2bf(a.w);
        v[4] = f2bf(b.x); v[5] = f2bf(b.y); v[6] = f2bf(b.z); v[7] = f2bf(b.w);
        *(ushort8*)(wfg + i * 8) = v;
        return;
    }
    // histogram
    hist[t] = 0; __syncthreads();
    int i = ((bid - h2bfB - 4) * 256 + t) * 4;
    if (i + 3 < E) {
        int4 d = *(const int4*)&dst[i];
        atomicAdd(&hist[d.x >> shift], 1);
        atomicAdd(&hist[d.y >> shift], 1);
        atomicAdd(&hist[d.z >> shift], 1);
        atomicAdd(&hist[d.w >> shift], 1);
    } else {
        for (int e = i; e < E; ++e) atomicAdd(&hist[dst[e] >> shift], 1);
    }
    __syncthreads();
    if (hist[t]) atomicAdd(&bsize[t], hist[t]);
}

// ---- A2: exclusive scan of bucket sizes (single block) ----
__global__ void __launch_bounds__(256)
bscan_kernel(const int* __restrict__ bsize, int* __restrict__ bases,
             int* __restrict__ cursors, int NB, int E)
{
    __shared__ int s[256];
    int t = threadIdx.x;
    int v = (t < NB) ? bsize[t] : 0;
    s[t] = v; __syncthreads();
    for (int o = 1; o < 256; o <<= 1) {
        int u = (t >= o) ? s[t - o] : 0;
        __syncthreads();
        s[t] += u; __syncthreads();
    }
    int ex = s[t] - v;
    if (t < NB) { bases[t] = ex; cursors[t] = ex; }
    if (t == 0) bases[NB] = E;
}

// ---- A3: scatter packed (src<<shift | dst&mask) into bucket regions ----
__global__ void __launch_bounds__(256)
scatter_pairs_kernel(const int* __restrict__ src, const int* __restrict__ dst,
                     int* __restrict__ cursors, int* __restrict__ pairs,
                     int E, int shift)
{
    __shared__ int hist[256];
    __shared__ int chunk[256];
    int t = threadIdx.x;
    hist[t] = 0;
    __syncthreads();
    int base = blockIdx.x * 4096;
    int s_[16], d_[16];
    #pragma unroll
    for (int r = 0; r < 4; ++r) {
        int e = base + r * 1024 + t * 4;
        if (e + 3 < E) {
            *(int4*)&s_[r * 4] = *(const int4*)&src[e];
            *(int4*)&d_[r * 4] = *(const int4*)&dst[e];
        } else {
            #pragma unroll
            for (int j = 0; j < 4; ++j) {
                int ee = e + j;
                s_[r * 4 + j] = (ee < E) ? src[ee] : -1;
                d_[r * 4 + j] = (ee < E) ? dst[ee] : -1;
            }
        }
    }
    #pragma unroll
    for (int i = 0; i < 16; ++i)
        if (d_[i] >= 0) atomicAdd(&hist[d_[i] >> shift], 1);
    __syncthreads();
    chunk[t] = hist[t] ? atomicAdd(&cursors[t], hist[t]) : 0;
    hist[t] = 0;
    __syncthreads();
    int mask = (1 << shift) - 1;
    #pragma unroll
    for (int i = 0; i < 16; ++i) {
        if (d_[i] >= 0) {
            int bk = d_[i] >> shift;
            int pos = atomicAdd(&hist[bk], 1);
            pairs[chunk[bk] + pos] = (s_[i] << shift) | (d_[i] & mask);
        }
    }
}

// ---- B: per-bucket counting sort -> off + adj (contiguous region) ----
__global__ void __launch_bounds__(256)
bucket_csr_kernel(const int* __restrict__ pairs, const int* __restrict__ bases,
                  int* __restrict__ off, int* __restrict__ adj,
                  int N, int E, int shift)
{
    __shared__ int cnt[512];       // requires (1<<shift) <= 512
    __shared__ int sums[256];
    int b = blockIdx.x, t = threadIdx.x;
    int nb0 = b << shift;
    int nn = min(1 << shift, N - nb0);
    int mask = (1 << shift) - 1;
    cnt[t] = 0; cnt[t + 256] = 0;
    __syncthreads();
    int e0 = bases[b], e1 = bases[b + 1];
    for (int e = e0 + t; e < e1; e += 256)
        atomicAdd(&cnt[pairs[e] & mask], 1);
    __syncthreads();
    int a = cnt[2 * t], c = cnt[2 * t + 1];
    int s = a + c;
    sums[t] = s; __syncthreads();
    for (int o = 1; o < 256; o <<= 1) {
        int u = (t >= o) ? sums[t - o] : 0;
        __syncthreads();
        sums[t] += u; __syncthreads();
    }
    int ex = sums[t] - s;
    if (2 * t     < nn) off[nb0 + 2 * t]     = e0 + ex;
    if (2 * t + 1 < nn) off[nb0 + 2 * t + 1] = e0 + ex + a;
    cnt[2 * t] = ex; cnt[2 * t + 1] = ex + a;
    __syncthreads();
    for (int e = e0 + t; e < e1; e += 256) {
        int pk = pairs[e];
        int pos = atomicAdd(&cnt[pk & mask], 1);
        adj[e0 + pos] = pk >> shift;
    }
    if (b == 0 && t == 0) off[N] = E;
}

// ---- Fused gather-mean + MFMA. 512 threads = 8 waves, 128 nodes/block.
// xl: [128 rows][16 chunks of 16B], chunk XOR-swizzled (chunk ^= row&7) ->
// A-frag ds_read_b128 conflict-free with no padding (32 KB exact).
// Wfrag: global frag-order bf16, straight-copied to LDS (16 KB, linear reads).
__global__ void __launch_bounds__(512, 3)
sage_mfma_kernel(const unsigned short* __restrict__ hbf, const int* __restrict__ adj,
                 const int* __restrict__ off, const unsigned short* __restrict__ wfg,
                 const float* __restrict__ bias, float* __restrict__ out, int N)
{
    __shared__ unsigned short xl[BN * 128];   // 32768 B
    __shared__ unsigned short wl[1024 * 8];   // 16384 B

    int t = threadIdx.x;
    int lane = t & 63, w = t >> 6;
    int node0 = blockIdx.x * BN;

    // stage Wfrag -> LDS (straight copy, 1024 ushort8)
    #pragma unroll
    for (int it = 0; it < 2; ++it) {
        int i = t + it * 512;
        *(ushort8*)&wl[i * 8] = *(const ushort8*)&wfg[(size_t)i * 8];
    }

    // stage self features -> xl chunks 0..7 (swizzled)
    #pragma unroll
    for (int it = 0; it < 2; ++it) {
        int i = t + it * 512;                 // 1024 = 128 rows x 8 chunks
        int n = i >> 3, c8 = i & 7;
        int node = node0 + n;
        ushort8 v = {};
        if (node < N) v = *(const ushort8*)&hbf[(size_t)node * FEAT + c8 * 8];
        *(ushort8*)&xl[(n * 16 + (c8 ^ (n & 7))) * 8] = v;
    }

    // gather neighbor means -> xl chunks 8..15 (swizzled)
    {
        int sub = lane >> 3;    // edge slot 0..7
        int f8  = lane & 7;     // ushort8 index within row
        int wnode0 = node0 + w * 16;

        int o0 = 0, o1 = 0;
        if (wnode0 < N) { o0 = off[wnode0]; o1 = off[wnode0 + 1]; }
        int idxA = (o0 + sub     < o1) ? adj[o0 + sub]     : -1;
        int idxB = (o0 + 8 + sub < o1) ? adj[o0 + 8 + sub] : -1;

        for (int q = 0; q < 16; ++q) {
            int node = wnode0 + q;
            int o2 = o1;
            if (q < 15 && node + 1 < N) o2 = off[node + 2];

            ushort8 rA, rB;
            bool vA = (idxA >= 0), vB = (idxB >= 0);
            if (vA) rA = *(const ushort8*)&hbf[(size_t)idxA * FEAT + f8 * 8];
            if (vB) rB = *(const ushort8*)&hbf[(size_t)idxB * FEAT + f8 * 8];

            int nA = -1, nB = -1;
            if (q < 15) {
                nA = (o1 + sub     < o2) ? adj[o1 + sub]     : -1;
                nB = (o1 + 8 + sub < o2) ? adj[o1 + 8 + sub] : -1;
            }

            float acc[8] = {0.f, 0.f, 0.f, 0.f, 0.f, 0.f, 0.f, 0.f};
            if (vA) {
                #pragma unroll
                for (int j = 0; j < 8; ++j) acc[j] += bf2f(rA[j]);
            }
            if (vB) {
                #pragma unroll
                for (int j = 0; j < 8; ++j) acc[j] += bf2f(rB[j]);
            }
            for (int base = o0 + 16; base < o1; base += 8) {   // deg > 16 tail
                int e = base + sub;
                if (e < o1) {
                    ushort8 r = *(const ushort8*)&hbf[(size_t)adj[e] * FEAT + f8 * 8];
                    #pragma unroll
                    for (int j = 0; j < 8; ++j) acc[j] += bf2f(r[j]);
                }
            }

            #pragma unroll
            for (int j = 0; j < 8; ++j) {
                float v = acc[j];
                v += __shfl_xor(v, 8);
                v += __shfl_xor(v, 16);
                v += __shfl_xor(v, 32);
                acc[j] = v;
            }
            if (sub == 0) {
                float inv = 1.0f / fmaxf((float)(o1 - o0), 1.0f);
                ushort8 m;
                #pragma unroll
                for (int j = 0; j < 8; ++j) m[j] = f2bf(acc[j] * inv);
                int nl = w * 16 + q;
                *(ushort8*)&xl[(nl * 16 + ((8 + f8) ^ (nl & 7))) * 8] = m;
            }
            o0 = o1; o1 = o2; idxA = nA; idxB = nB;
        }
    }
    __syncthreads();

    // MFMA: wave w -> nodes [w*16, w*16+16). 16 x mfma_f32_16x16x32_bf16.
    f32x4 acc[4] = {};
    int r = w * 16 + (lane & 15);
    #pragma unroll
    for (int ks = 0; ks < 4; ++ks) {
        int chunk = ks * 4 + (lane >> 4);
        bf16x8 a = *(const bf16x8*)&xl[(r * 16 + (chunk ^ (r & 7))) * 8];
        #pragma unroll
        for (int nt = 0; nt < 4; ++nt) {
            bf16x8 b = *(const bf16x8*)&wl[((ks * 4 + nt) * 64 + lane) * 8];
            acc[nt] = __builtin_amdgcn_mfma_f32_16x16x32_bf16(a, b, acc[nt], 0, 0, 0);
        }
    }

    // store: C/D layout col=lane&15, row=(lane>>4)*4+reg (m89-verified)
    int col   = lane & 15;
    int rbase = node0 + w * 16 + (lane >> 4) * 4;
    #pragma unroll
    for (int nt = 0; nt < 4; ++nt) {
        float bj = bias[nt * 16 + col];
        #pragma unroll
        for (int rr = 0; rr < 4; ++rr) {
            int node = rbase + rr;
            if (node < N) {
                float vv = acc[nt][rr] + bj;
                out[(size_t)node * FEAT + nt * 16 + col] = fmaxf(vv, 0.f);
            }
        }
    }
}

extern "C" void kernel_launch(void* const* d_in, const int* in_sizes, int n_in,
                              void* d_out, int out_size, void* d_ws, size_t ws_size,
                              hipStream_t stream)
{
    const float* h   = (const float*)d_in[0];
    const int*   src = (const int*)d_in[1];
    const int*   dst = (const int*)d_in[2];
    const float* W   = (const float*)d_in[3];
    const float* b   = (const float*)d_in[4];
    float* out = (float*)d_out;

    int N = in_sizes[0] / FEAT;
    int E = in_sizes[1];

    int shift = 0;
    while (((N - 1) >> shift) >= 256) ++shift;     // N=100K -> shift=9, NB=196
    int NB = ((N - 1) >> shift) + 1;

    // ws: hbf[N*64 ush] | wfg[8192 ush] | pairs[E] | adj[E] | off[N+1] |
    //     bsize[256] | bases[257] | cursors[256]   (~21.2 MB)
    unsigned short* hbf = (unsigned short*)d_ws;
    unsigned short* wfg = hbf + (size_t)N * FEAT;
    int*  pairs   = (int*)(wfg + 8192);
    int*  adj     = pairs + E;
    int*  off     = adj + E;
    int*  bsize   = off + (N + 1);
    int*  bases   = bsize + 256;
    int*  cursors = bases + 257;

    hipMemsetAsync(bsize, 0, 256 * sizeof(int), stream);

    int total8 = N * (FEAT / 8);
    int h2bfB  = (total8 + 255) / 256;
    int histB  = (E + 1023) / 1024;
    prep_kernel<<<h2bfB + 4 + histB, 256, 0, stream>>>(h, hbf, total8, W, wfg,
                                                       dst, bsize, E, shift, h2bfB);

    bscan_kernel<<<1, 256, 0, stream>>>(bsize, bases, cursors, NB, E);

    int spblocks = (E + 4095) / 4096;
    scatter_pairs_kernel<<<spblocks, 256, 0, stream>>>(src, dst, cursors, pairs, E, shift);

    bucket_csr_kernel<<<NB, 256, 0, stream>>>(pairs, bases, off, adj, N, E, shift);

    int gblocks = (N + BN - 1) / BN;
    sage_mfma_kernel<<<gblocks, 512, 0, stream>>>(hbf, adj, off, wfg, b, out, N);
}

// Round 9
// 122.049 us; speedup vs baseline: 2.0216x; 1.0766x over previous
//
#include <hip/hip_runtime.h>

#define FEAT 64
#define BN 128       // nodes per MFMA block (8 waves x 16 nodes)

typedef __attribute__((ext_vector_type(8))) __bf16 bf16x8;
typedef __attribute__((ext_vector_type(8))) unsigned short ushort8;
typedef __attribute__((ext_vector_type(4))) float f32x4;

__device__ inline unsigned short f2bf(float f) {
    union { float f; unsigned u; } c; c.f = f;
    unsigned u = c.u;
    return (unsigned short)((u + 0x7fffu + ((u >> 16) & 1u)) >> 16);  // RNE
}
__device__ inline float bf2f(unsigned short s) {
    union { unsigned u; float f; } c; c.u = ((unsigned)s) << 16; return c.f;
}

// ---- Prep (fused): [0,h2bfB) h fp32->bf16 | [h2bfB,+4) W->Wfrag bf16 |
// rest: bucket histogram of dst>>shift ----
__global__ void __launch_bounds__(256)
prep_kernel(const float* __restrict__ h, unsigned short* __restrict__ hbf,
            int total8, const float* __restrict__ W, unsigned short* __restrict__ wfg,
            const int* __restrict__ dst, int* __restrict__ bsize, int E,
            int shift, int h2bfB)
{
    __shared__ int hist[256];
    int bid = blockIdx.x, t = threadIdx.x;

    if (bid < h2bfB) {                       // h fp32 -> bf16
        int i = bid * 256 + t;
        if (i < total8) {
            const float4* p = (const float4*)(h + (size_t)i * 8);
            float4 a = p[0], b = p[1];
            ushort8 v;
            v[0] = f2bf(a.x); v[1] = f2bf(a.y); v[2] = f2bf(a.z); v[3] = f2bf(a.w);
            v[4] = f2bf(b.x); v[5] = f2bf(b.y); v[6] = f2bf(b.z); v[7] = f2bf(b.w);
            *(ushort8*)(hbf + (size_t)i * 8) = v;
        }
        return;
    }
    if (bid < h2bfB + 4) {                   // W (64x128 f32) -> frag-order bf16
        int i = (bid - h2bfB) * 256 + t;     // 0..1023 = (ks*4+nt)*64 + lane
        int ksnt = i >> 6, lane = i & 63;
        int row = (ksnt & 3) * 16 + (lane & 15);
        int kb  = (ksnt >> 2) * 32 + (lane >> 4) * 8;
        const float4* p = (const float4*)(W + row * 128 + kb);
        float4 a = p[0], b = p[1];
        ushort8 v;
        v[0] = f2bf(a.x); v[1] = f2bf(a.y); v[2] = f2bf(a.z); v[3] = f2bf(a.w);
        v[4] = f2bf(b.x); v[5] = f2bf(b.y); v[6] = f2bf(b.z); v[7] = f2bf(b.w);
        *(ushort8*)(wfg + i * 8) = v;
        return;
    }
    // histogram
    hist[t] = 0; __syncthreads();
    int i = ((bid - h2bfB - 4) * 256 + t) * 4;
    if (i + 3 < E) {
        int4 d = *(const int4*)&dst[i];
        atomicAdd(&hist[d.x >> shift], 1);
        atomicAdd(&hist[d.y >> shift], 1);
        atomicAdd(&hist[d.z >> shift], 1);
        atomicAdd(&hist[d.w >> shift], 1);
    } else {
        for (int e = i; e < E; ++e) atomicAdd(&hist[dst[e] >> shift], 1);
    }
    __syncthreads();
    if (hist[t]) atomicAdd(&bsize[t], hist[t]);
}

// ---- A2: exclusive scan of bucket sizes (single block) ----
__global__ void __launch_bounds__(256)
bscan_kernel(const int* __restrict__ bsize, int* __restrict__ bases,
             int* __restrict__ cursors, int NB, int E)
{
    __shared__ int s[256];
    int t = threadIdx.x;
    int v = (t < NB) ? bsize[t] : 0;
    s[t] = v; __syncthreads();
    for (int o = 1; o < 256; o <<= 1) {
        int u = (t >= o) ? s[t - o] : 0;
        __syncthreads();
        s[t] += u; __syncthreads();
    }
    int ex = s[t] - v;
    if (t < NB) { bases[t] = ex; cursors[t] = ex; }
    if (t == 0) bases[NB] = E;
}

// ---- A3: scatter packed (src<<shift | dst&mask) into bucket regions ----
__global__ void __launch_bounds__(256)
scatter_pairs_kernel(const int* __restrict__ src, const int* __restrict__ dst,
                     int* __restrict__ cursors, int* __restrict__ pairs,
                     int E, int shift)
{
    __shared__ int hist[256];
    __shared__ int chunk[256];
    int t = threadIdx.x;
    hist[t] = 0;
    __syncthreads();
    int base = blockIdx.x * 4096;
    int s_[16], d_[16];
    #pragma unroll
    for (int r = 0; r < 4; ++r) {
        int e = base + r * 1024 + t * 4;
        if (e + 3 < E) {
            *(int4*)&s_[r * 4] = *(const int4*)&src[e];
            *(int4*)&d_[r * 4] = *(const int4*)&dst[e];
        } else {
            #pragma unroll
            for (int j = 0; j < 4; ++j) {
                int ee = e + j;
                s_[r * 4 + j] = (ee < E) ? src[ee] : -1;
                d_[r * 4 + j] = (ee < E) ? dst[ee] : -1;
            }
        }
    }
    #pragma unroll
    for (int i = 0; i < 16; ++i)
        if (d_[i] >= 0) atomicAdd(&hist[d_[i] >> shift], 1);
    __syncthreads();
    chunk[t] = hist[t] ? atomicAdd(&cursors[t], hist[t]) : 0;
    hist[t] = 0;
    __syncthreads();
    int mask = (1 << shift) - 1;
    #pragma unroll
    for (int i = 0; i < 16; ++i) {
        if (d_[i] >= 0) {
            int bk = d_[i] >> shift;
            int pos = atomicAdd(&hist[bk], 1);
            pairs[chunk[bk] + pos] = (s_[i] << shift) | (d_[i] & mask);
        }
    }
}

// ---- B: per-bucket counting sort -> off + adj (contiguous region) ----
__global__ void __launch_bounds__(256)
bucket_csr_kernel(const int* __restrict__ pairs, const int* __restrict__ bases,
                  int* __restrict__ off, int* __restrict__ adj,
                  int N, int E, int shift)
{
    __shared__ int cnt[512];       // requires (1<<shift) <= 512
    __shared__ int sums[256];
    int b = blockIdx.x, t = threadIdx.x;
    int nb0 = b << shift;
    int nn = min(1 << shift, N - nb0);
    int mask = (1 << shift) - 1;
    cnt[t] = 0; cnt[t + 256] = 0;
    __syncthreads();
    int e0 = bases[b], e1 = bases[b + 1];
    for (int e = e0 + t; e < e1; e += 256)
        atomicAdd(&cnt[pairs[e] & mask], 1);
    __syncthreads();
    int a = cnt[2 * t], c = cnt[2 * t + 1];
    int s = a + c;
    sums[t] = s; __syncthreads();
    for (int o = 1; o < 256; o <<= 1) {
        int u = (t >= o) ? sums[t - o] : 0;
        __syncthreads();
        sums[t] += u; __syncthreads();
    }
    int ex = sums[t] - s;
    if (2 * t     < nn) off[nb0 + 2 * t]     = e0 + ex;
    if (2 * t + 1 < nn) off[nb0 + 2 * t + 1] = e0 + ex + a;
    cnt[2 * t] = ex; cnt[2 * t + 1] = ex + a;
    __syncthreads();
    for (int e = e0 + t; e < e1; e += 256) {
        int pk = pairs[e];
        int pos = atomicAdd(&cnt[pk & mask], 1);
        adj[e0 + pos] = pk >> shift;
    }
    if (b == 0 && t == 0) off[N] = E;
}

// ---- Gather: ONE NODE PER WAVE (node-level TLP; no LDS, max occupancy).
// lane = (slot 0..7, ushort8 0..7): 8 rows per issue, A+B batches -> 16 rows
// in flight. Result (bf16 mean) written to the first 128B of the node's
// d_out row (same-row-only hazard: MFMA kernel stages it before overwrite).
__global__ void __launch_bounds__(256)
gather_kernel(const unsigned short* __restrict__ hbf, const int* __restrict__ adj,
              const int* __restrict__ off, unsigned short* __restrict__ hn,
              int N)
{
    int node = (blockIdx.x * 256 + threadIdx.x) >> 6;
    if (node >= N) return;
    int lane = threadIdx.x & 63;
    int sub = lane >> 3, f8 = lane & 7;

    int o0 = off[node], o1 = off[node + 1];
    float acc[8] = {0.f, 0.f, 0.f, 0.f, 0.f, 0.f, 0.f, 0.f};
    for (int base = o0; base < o1; base += 16) {
        int eA = base + sub, eB = base + 8 + sub;
        int iA = (eA < o1) ? adj[eA] : -1;
        int iB = (eB < o1) ? adj[eB] : -1;
        ushort8 rA, rB;
        if (iA >= 0) rA = *(const ushort8*)&hbf[(size_t)iA * FEAT + f8 * 8];
        if (iB >= 0) rB = *(const ushort8*)&hbf[(size_t)iB * FEAT + f8 * 8];
        if (iA >= 0) {
            #pragma unroll
            for (int j = 0; j < 8; ++j) acc[j] += bf2f(rA[j]);
        }
        if (iB >= 0) {
            #pragma unroll
            for (int j = 0; j < 8; ++j) acc[j] += bf2f(rB[j]);
        }
    }
    // reduce across the 8 slots (lane bits 3,4,5)
    #pragma unroll
    for (int j = 0; j < 8; ++j) {
        float v = acc[j];
        v += __shfl_xor(v, 8);
        v += __shfl_xor(v, 16);
        v += __shfl_xor(v, 32);
        acc[j] = v;
    }
    if (sub == 0) {
        float inv = 1.0f / fmaxf((float)(o1 - o0), 1.0f);
        ushort8 m;
        #pragma unroll
        for (int j = 0; j < 8; ++j) m[j] = f2bf(acc[j] * inv);
        // d_out viewed as ushort: node's row = 128 ushorts (256B)
        *(ushort8*)&hn[(size_t)node * 128 + f8 * 8] = m;
    }
}

// ---- MFMA: pure staging + 16 mfma per wave. 512 threads, 128 nodes/block.
// xl: [128 rows][16 chunks of 16B], chunk XOR-swizzled (chunk ^= row&7).
// Self half from hbf; neighbor half from hn (= d_out bf16 region); both
// straight vectorized copies. Wfrag: frag-order bf16, linear copy.
__global__ void __launch_bounds__(512, 3)
sage_mfma_kernel(const unsigned short* __restrict__ hbf,
                 const unsigned short* __restrict__ hn,
                 const unsigned short* __restrict__ wfg,
                 const float* __restrict__ bias, float* __restrict__ out, int N)
{
    __shared__ unsigned short xl[BN * 128];   // 32768 B
    __shared__ unsigned short wl[1024 * 8];   // 16384 B

    int t = threadIdx.x;
    int lane = t & 63, w = t >> 6;
    int node0 = blockIdx.x * BN;

    // stage Wfrag -> LDS (straight copy, 1024 ushort8)
    #pragma unroll
    for (int it = 0; it < 2; ++it) {
        int i = t + it * 512;
        *(ushort8*)&wl[i * 8] = *(const ushort8*)&wfg[(size_t)i * 8];
    }

    // stage self features -> xl chunks 0..7 (swizzled)
    #pragma unroll
    for (int it = 0; it < 2; ++it) {
        int i = t + it * 512;                 // 1024 = 128 rows x 8 chunks
        int n = i >> 3, c8 = i & 7;
        int node = node0 + n;
        ushort8 v = {};
        if (node < N) v = *(const ushort8*)&hbf[(size_t)node * FEAT + c8 * 8];
        *(ushort8*)&xl[(n * 16 + (c8 ^ (n & 7))) * 8] = v;
    }

    // stage neighbor means -> xl chunks 8..15 (swizzled)
    #pragma unroll
    for (int it = 0; it < 2; ++it) {
        int i = t + it * 512;
        int n = i >> 3, c8 = i & 7;
        int node = node0 + n;
        ushort8 v = {};
        if (node < N) v = *(const ushort8*)&hn[(size_t)node * 128 + c8 * 8];
        *(ushort8*)&xl[(n * 16 + ((8 + c8) ^ (n & 7))) * 8] = v;
    }
    __syncthreads();

    // MFMA: wave w -> nodes [w*16, w*16+16). 16 x mfma_f32_16x16x32_bf16.
    f32x4 acc[4] = {};
    int r = w * 16 + (lane & 15);
    #pragma unroll
    for (int ks = 0; ks < 4; ++ks) {
        int chunk = ks * 4 + (lane >> 4);
        bf16x8 a = *(const bf16x8*)&xl[(r * 16 + (chunk ^ (r & 7))) * 8];
        #pragma unroll
        for (int nt = 0; nt < 4; ++nt) {
            bf16x8 b = *(const bf16x8*)&wl[((ks * 4 + nt) * 64 + lane) * 8];
            acc[nt] = __builtin_amdgcn_mfma_f32_16x16x32_bf16(a, b, acc[nt], 0, 0, 0);
        }
    }

    // store: C/D layout col=lane&15, row=(lane>>4)*4+reg (m89-verified)
    int col   = lane & 15;
    int rbase = node0 + w * 16 + (lane >> 4) * 4;
    #pragma unroll
    for (int nt = 0; nt < 4; ++nt) {
        float bj = bias[nt * 16 + col];
        #pragma unroll
        for (int rr = 0; rr < 4; ++rr) {
            int node = rbase + rr;
            if (node < N) {
                float vv = acc[nt][rr] + bj;
                out[(size_t)node * FEAT + nt * 16 + col] = fmaxf(vv, 0.f);
            }
        }
    }
}

extern "C" void kernel_launch(void* const* d_in, const int* in_sizes, int n_in,
                              void* d_out, int out_size, void* d_ws, size_t ws_size,
                              hipStream_t stream)
{
    const float* h   = (const float*)d_in[0];
    const int*   src = (const int*)d_in[1];
    const int*   dst = (const int*)d_in[2];
    const float* W   = (const float*)d_in[3];
    const float* b   = (const float*)d_in[4];
    float* out = (float*)d_out;

    int N = in_sizes[0] / FEAT;
    int E = in_sizes[1];

    int shift = 0;
    while (((N - 1) >> shift) >= 256) ++shift;     // N=100K -> shift=9, NB=196
    int NB = ((N - 1) >> shift) + 1;

    // ws: hbf[N*64 ush] | wfg[8192 ush] | pairs[E] | adj[E] | off[N+1] |
    //     bsize[256] | bases[257] | cursors[256]   (~21.2 MB)
    unsigned short* hbf = (unsigned short*)d_ws;
    unsigned short* wfg = hbf + (size_t)N * FEAT;
    int*  pairs   = (int*)(wfg + 8192);
    int*  adj     = pairs + E;
    int*  off     = adj + E;
    int*  bsize   = off + (N + 1);
    int*  bases   = bsize + 256;
    int*  cursors = bases + 257;

    hipMemsetAsync(bsize, 0, 256 * sizeof(int), stream);

    int total8 = N * (FEAT / 8);
    int h2bfB  = (total8 + 255) / 256;
    int histB  = (E + 1023) / 1024;
    prep_kernel<<<h2bfB + 4 + histB, 256, 0, stream>>>(h, hbf, total8, W, wfg,
                                                       dst, bsize, E, shift, h2bfB);

    bscan_kernel<<<1, 256, 0, stream>>>(bsize, bases, cursors, NB, E);

    int spblocks = (E + 4095) / 4096;
    scatter_pairs_kernel<<<spblocks, 256, 0, stream>>>(src, dst, cursors, pairs, E, shift);

    bucket_csr_kernel<<<NB, 256, 0, stream>>>(pairs, bases, off, adj, N, E, shift);

    // hn (bf16 neighbor means) lives in the first 128B of each d_out row
    unsigned short* hn = (unsigned short*)d_out;
    int gwaves = (N + 3) / 4;                      // 4 waves (nodes) per block
    gather_kernel<<<gwaves, 256, 0, stream>>>(hbf, adj, off, hn, N);

    int gblocks = (N + BN - 1) / BN;
    sage_mfma_kernel<<<gblocks, 512, 0, stream>>>(hbf, hn, wfg, b, out, N);
}

// Round 10
// 117.832 us; speedup vs baseline: 2.0940x; 1.0358x over previous
//
#include <hip/hip_runtime.h>

#define FEAT 64
#define BN 128       // nodes per MFMA block (8 waves x 16 nodes)

typedef __attribute__((ext_vector_type(8))) __bf16 bf16x8;
typedef __attribute__((ext_vector_type(8))) unsigned short ushort8;
typedef __attribute__((ext_vector_type(4))) float f32x4;

__device__ inline unsigned short f2bf(float f) {
    union { float f; unsigned u; } c; c.f = f;
    unsigned u = c.u;
    return (unsigned short)((u + 0x7fffu + ((u >> 16) & 1u)) >> 16);  // RNE
}
__device__ inline float bf2f(unsigned short s) {
    union { unsigned u; float f; } c; c.u = ((unsigned)s) << 16; return c.f;
}

// ---- tiny zero (replaces in-graph hipMemsetAsync: rocclr fill cost ~40us) ----
__global__ void __launch_bounds__(256)
zero_kernel(int* __restrict__ p, int n)
{
    int i = threadIdx.x;
    if (i < n) p[i] = 0;
}

// ---- Prep (fused): [0,h2bfB) h fp32->bf16 | [h2bfB,+4) W->Wfrag bf16 |
// rest: bucket histogram of dst>>shift ----
__global__ void __launch_bounds__(256)
prep_kernel(const float* __restrict__ h, unsigned short* __restrict__ hbf,
            int total8, const float* __restrict__ W, unsigned short* __restrict__ wfg,
            const int* __restrict__ dst, int* __restrict__ bsize, int E,
            int shift, int h2bfB)
{
    __shared__ int hist[256];
    int bid = blockIdx.x, t = threadIdx.x;

    if (bid < h2bfB) {                       // h fp32 -> bf16
        int i = bid * 256 + t;
        if (i < total8) {
            const float4* p = (const float4*)(h + (size_t)i * 8);
            float4 a = p[0], b = p[1];
            ushort8 v;
            v[0] = f2bf(a.x); v[1] = f2bf(a.y); v[2] = f2bf(a.z); v[3] = f2bf(a.w);
            v[4] = f2bf(b.x); v[5] = f2bf(b.y); v[6] = f2bf(b.z); v[7] = f2bf(b.w);
            *(ushort8*)(hbf + (size_t)i * 8) = v;
        }
        return;
    }
    if (bid < h2bfB + 4) {                   // W (64x128 f32) -> frag-order bf16
        int i = (bid - h2bfB) * 256 + t;     // 0..1023 = (ks*4+nt)*64 + lane
        int ksnt = i >> 6, lane = i & 63;
        int row = (ksnt & 3) * 16 + (lane & 15);
        int kb  = (ksnt >> 2) * 32 + (lane >> 4) * 8;
        const float4* p = (const float4*)(W + row * 128 + kb);
        float4 a = p[0], b = p[1];
        ushort8 v;
        v[0] = f2bf(a.x); v[1] = f2bf(a.y); v[2] = f2bf(a.z); v[3] = f2bf(a.w);
        v[4] = f2bf(b.x); v[5] = f2bf(b.y); v[6] = f2bf(b.z); v[7] = f2bf(b.w);
        *(ushort8*)(wfg + i * 8) = v;
        return;
    }
    // histogram
    hist[t] = 0; __syncthreads();
    int i = ((bid - h2bfB - 4) * 256 + t) * 4;
    if (i + 3 < E) {
        int4 d = *(const int4*)&dst[i];
        atomicAdd(&hist[d.x >> shift], 1);
        atomicAdd(&hist[d.y >> shift], 1);
        atomicAdd(&hist[d.z >> shift], 1);
        atomicAdd(&hist[d.w >> shift], 1);
    } else {
        for (int e = i; e < E; ++e) atomicAdd(&hist[dst[e] >> shift], 1);
    }
    __syncthreads();
    if (hist[t]) atomicAdd(&bsize[t], hist[t]);
}

// ---- A2: exclusive scan of bucket sizes (single block) ----
__global__ void __launch_bounds__(256)
bscan_kernel(const int* __restrict__ bsize, int* __restrict__ bases,
             int* __restrict__ cursors, int NB, int E)
{
    __shared__ int s[256];
    int t = threadIdx.x;
    int v = (t < NB) ? bsize[t] : 0;
    s[t] = v; __syncthreads();
    for (int o = 1; o < 256; o <<= 1) {
        int u = (t >= o) ? s[t - o] : 0;
        __syncthreads();
        s[t] += u; __syncthreads();
    }
    int ex = s[t] - v;
    if (t < NB) { bases[t] = ex; cursors[t] = ex; }
    if (t == 0) bases[NB] = E;
}

// ---- A3: scatter packed (src<<shift | dst&mask) into bucket regions ----
__global__ void __launch_bounds__(256)
scatter_pairs_kernel(const int* __restrict__ src, const int* __restrict__ dst,
                     int* __restrict__ cursors, int* __restrict__ pairs,
                     int E, int shift)
{
    __shared__ int hist[256];
    __shared__ int chunk[256];
    int t = threadIdx.x;
    hist[t] = 0;
    __syncthreads();
    int base = blockIdx.x * 4096;
    int s_[16], d_[16];
    #pragma unroll
    for (int r = 0; r < 4; ++r) {
        int e = base + r * 1024 + t * 4;
        if (e + 3 < E) {
            *(int4*)&s_[r * 4] = *(const int4*)&src[e];
            *(int4*)&d_[r * 4] = *(const int4*)&dst[e];
        } else {
            #pragma unroll
            for (int j = 0; j < 4; ++j) {
                int ee = e + j;
                s_[r * 4 + j] = (ee < E) ? src[ee] : -1;
                d_[r * 4 + j] = (ee < E) ? dst[ee] : -1;
            }
        }
    }
    #pragma unroll
    for (int i = 0; i < 16; ++i)
        if (d_[i] >= 0) atomicAdd(&hist[d_[i] >> shift], 1);
    __syncthreads();
    chunk[t] = hist[t] ? atomicAdd(&cursors[t], hist[t]) : 0;
    hist[t] = 0;
    __syncthreads();
    int mask = (1 << shift) - 1;
    #pragma unroll
    for (int i = 0; i < 16; ++i) {
        if (d_[i] >= 0) {
            int bk = d_[i] >> shift;
            int pos = atomicAdd(&hist[bk], 1);
            pairs[chunk[bk] + pos] = (s_[i] << shift) | (d_[i] & mask);
        }
    }
}

// ---- B: per-bucket counting sort -> off + adj (contiguous region) ----
__global__ void __launch_bounds__(256)
bucket_csr_kernel(const int* __restrict__ pairs, const int* __restrict__ bases,
                  int* __restrict__ off, int* __restrict__ adj,
                  int N, int E, int shift)
{
    __shared__ int cnt[512];       // requires (1<<shift) <= 512
    __shared__ int sums[256];
    int b = blockIdx.x, t = threadIdx.x;
    int nb0 = b << shift;
    int nn = min(1 << shift, N - nb0);
    int mask = (1 << shift) - 1;
    cnt[t] = 0; cnt[t + 256] = 0;
    __syncthreads();
    int e0 = bases[b], e1 = bases[b + 1];
    for (int e = e0 + t; e < e1; e += 256)
        atomicAdd(&cnt[pairs[e] & mask], 1);
    __syncthreads();
    int a = cnt[2 * t], c = cnt[2 * t + 1];
    int s = a + c;
    sums[t] = s; __syncthreads();
    for (int o = 1; o < 256; o <<= 1) {
        int u = (t >= o) ? sums[t - o] : 0;
        __syncthreads();
        sums[t] += u; __syncthreads();
    }
    int ex = sums[t] - s;
    if (2 * t     < nn) off[nb0 + 2 * t]     = e0 + ex;
    if (2 * t + 1 < nn) off[nb0 + 2 * t + 1] = e0 + ex + a;
    cnt[2 * t] = ex; cnt[2 * t + 1] = ex + a;
    __syncthreads();
    for (int e = e0 + t; e < e1; e += 256) {
        int pk = pairs[e];
        int pos = atomicAdd(&cnt[pk & mask], 1);
        adj[e0 + pos] = pk >> shift;
    }
    if (b == 0 && t == 0) off[N] = E;
}

// ---- Gather: ONE NODE PER WAVE (node-level TLP; no LDS, max occupancy).
// lane = (slot 0..7, ushort8 0..7): 8 rows per issue, A+B batches -> 16 rows
// in flight. Result (bf16 mean) written to the first 128B of the node's
// d_out row (same-row-only hazard: MFMA kernel stages it before overwrite).
__global__ void __launch_bounds__(256)
gather_kernel(const unsigned short* __restrict__ hbf, const int* __restrict__ adj,
              const int* __restrict__ off, unsigned short* __restrict__ hn,
              int N)
{
    int node = (blockIdx.x * 256 + threadIdx.x) >> 6;
    if (node >= N) return;
    int lane = threadIdx.x & 63;
    int sub = lane >> 3, f8 = lane & 7;

    int o0 = off[node], o1 = off[node + 1];
    float acc[8] = {0.f, 0.f, 0.f, 0.f, 0.f, 0.f, 0.f, 0.f};
    for (int base = o0; base < o1; base += 16) {
        int eA = base + sub, eB = base + 8 + sub;
        int iA = (eA < o1) ? adj[eA] : -1;
        int iB = (eB < o1) ? adj[eB] : -1;
        ushort8 rA, rB;
        if (iA >= 0) rA = *(const ushort8*)&hbf[(size_t)iA * FEAT + f8 * 8];
        if (iB >= 0) rB = *(const ushort8*)&hbf[(size_t)iB * FEAT + f8 * 8];
        if (iA >= 0) {
            #pragma unroll
            for (int j = 0; j < 8; ++j) acc[j] += bf2f(rA[j]);
        }
        if (iB >= 0) {
            #pragma unroll
            for (int j = 0; j < 8; ++j) acc[j] += bf2f(rB[j]);
        }
    }
    // reduce across the 8 slots (lane bits 3,4,5)
    #pragma unroll
    for (int j = 0; j < 8; ++j) {
        float v = acc[j];
        v += __shfl_xor(v, 8);
        v += __shfl_xor(v, 16);
        v += __shfl_xor(v, 32);
        acc[j] = v;
    }
    if (sub == 0) {
        float inv = 1.0f / fmaxf((float)(o1 - o0), 1.0f);
        ushort8 m;
        #pragma unroll
        for (int j = 0; j < 8; ++j) m[j] = f2bf(acc[j] * inv);
        // d_out viewed as ushort: node's row = 128 ushorts (256B)
        *(ushort8*)&hn[(size_t)node * 128 + f8 * 8] = m;
    }
}

// ---- MFMA: pure staging + 16 mfma per wave. 512 threads, 128 nodes/block.
// xl: [128 rows][16 chunks of 16B], chunk XOR-swizzled (chunk ^= row&7).
// Self half from hbf; neighbor half from hn (= d_out bf16 region); both
// straight vectorized copies. Wfrag: frag-order bf16, linear copy.
__global__ void __launch_bounds__(512, 3)
sage_mfma_kernel(const unsigned short* __restrict__ hbf,
                 const unsigned short* __restrict__ hn,
                 const unsigned short* __restrict__ wfg,
                 const float* __restrict__ bias, float* __restrict__ out, int N)
{
    __shared__ unsigned short xl[BN * 128];   // 32768 B
    __shared__ unsigned short wl[1024 * 8];   // 16384 B

    int t = threadIdx.x;
    int lane = t & 63, w = t >> 6;
    int node0 = blockIdx.x * BN;

    // stage Wfrag -> LDS (straight copy, 1024 ushort8)
    #pragma unroll
    for (int it = 0; it < 2; ++it) {
        int i = t + it * 512;
        *(ushort8*)&wl[i * 8] = *(const ushort8*)&wfg[(size_t)i * 8];
    }

    // stage self features -> xl chunks 0..7 (swizzled)
    #pragma unroll
    for (int it = 0; it < 2; ++it) {
        int i = t + it * 512;                 // 1024 = 128 rows x 8 chunks
        int n = i >> 3, c8 = i & 7;
        int node = node0 + n;
        ushort8 v = {};
        if (node < N) v = *(const ushort8*)&hbf[(size_t)node * FEAT + c8 * 8];
        *(ushort8*)&xl[(n * 16 + (c8 ^ (n & 7))) * 8] = v;
    }

    // stage neighbor means -> xl chunks 8..15 (swizzled)
    #pragma unroll
    for (int it = 0; it < 2; ++it) {
        int i = t + it * 512;
        int n = i >> 3, c8 = i & 7;
        int node = node0 + n;
        ushort8 v = {};
        if (node < N) v = *(const ushort8*)&hn[(size_t)node * 128 + c8 * 8];
        *(ushort8*)&xl[(n * 16 + ((8 + c8) ^ (n & 7))) * 8] = v;
    }
    __syncthreads();

    // MFMA: wave w -> nodes [w*16, w*16+16). 16 x mfma_f32_16x16x32_bf16.
    f32x4 acc[4] = {};
    int r = w * 16 + (lane & 15);
    #pragma unroll
    for (int ks = 0; ks < 4; ++ks) {
        int chunk = ks * 4 + (lane >> 4);
        bf16x8 a = *(const bf16x8*)&xl[(r * 16 + (chunk ^ (r & 7))) * 8];
        #pragma unroll
        for (int nt = 0; nt < 4; ++nt) {
            bf16x8 b = *(const bf16x8*)&wl[((ks * 4 + nt) * 64 + lane) * 8];
            acc[nt] = __builtin_amdgcn_mfma_f32_16x16x32_bf16(a, b, acc[nt], 0, 0, 0);
        }
    }

    // store: C/D layout col=lane&15, row=(lane>>4)*4+reg (m89-verified)
    int col   = lane & 15;
    int rbase = node0 + w * 16 + (lane >> 4) * 4;
    #pragma unroll
    for (int nt = 0; nt < 4; ++nt) {
        float bj = bias[nt * 16 + col];
        #pragma unroll
        for (int rr = 0; rr < 4; ++rr) {
            int node = rbase + rr;
            if (node < N) {
                float vv = acc[nt][rr] + bj;
                out[(size_t)node * FEAT + nt * 16 + col] = fmaxf(vv, 0.f);
            }
        }
    }
}

extern "C" void kernel_launch(void* const* d_in, const int* in_sizes, int n_in,
                              void* d_out, int out_size, void* d_ws, size_t ws_size,
                              hipStream_t stream)
{
    const float* h   = (const float*)d_in[0];
    const int*   src = (const int*)d_in[1];
    const int*   dst = (const int*)d_in[2];
    const float* W   = (const float*)d_in[3];
    const float* b   = (const float*)d_in[4];
    float* out = (float*)d_out;

    int N = in_sizes[0] / FEAT;
    int E = in_sizes[1];

    int shift = 0;
    while (((N - 1) >> shift) >= 256) ++shift;     // N=100K -> shift=9, NB=196
    int NB = ((N - 1) >> shift) + 1;

    // ws: hbf[N*64 ush] | wfg[8192 ush] | pairs[E] | adj[E] | off[N+1] |
    //     bsize[256] | bases[257] | cursors[256]   (~21.2 MB)
    unsigned short* hbf = (unsigned short*)d_ws;
    unsigned short* wfg = hbf + (size_t)N * FEAT;
    int*  pairs   = (int*)(wfg + 8192);
    int*  adj     = pairs + E;
    int*  off     = adj + E;
    int*  bsize   = off + (N + 1);
    int*  bases   = bsize + 256;
    int*  cursors = bases + 257;

    // in-graph hipMemsetAsync costs ~40us via rocclr fill; use our own kernel
    zero_kernel<<<1, 256, 0, stream>>>(bsize, 256);

    int total8 = N * (FEAT / 8);
    int h2bfB  = (total8 + 255) / 256;
    int histB  = (E + 1023) / 1024;
    prep_kernel<<<h2bfB + 4 + histB, 256, 0, stream>>>(h, hbf, total8, W, wfg,
                                                       dst, bsize, E, shift, h2bfB);

    bscan_kernel<<<1, 256, 0, stream>>>(bsize, bases, cursors, NB, E);

    int spblocks = (E + 4095) / 4096;
    scatter_pairs_kernel<<<spblocks, 256, 0, stream>>>(src, dst, cursors, pairs, E, shift);

    bucket_csr_kernel<<<NB, 256, 0, stream>>>(pairs, bases, off, adj, N, E, shift);

    // hn (bf16 neighbor means) lives in the first 128B of each d_out row
    unsigned short* hn = (unsigned short*)d_out;
    int gwaves = (N + 3) / 4;                      // 4 waves (nodes) per block
    gather_kernel<<<gwaves, 256, 0, stream>>>(hbf, adj, off, hn, N);

    int gblocks = (N + BN - 1) / BN;
    sage_mfma_kernel<<<gblocks, 512, 0, stream>>>(hbf, hn, wfg, b, out, N);
}